// Round 2
// baseline (221.489 us; speedup 1.0000x reference)
//
// MongeGapTransport: KNN gather + 5-layer MLP pushforward, bf16 I/O (confirmed).
// R17: R16 (214.6us) + two levers:
//  - hidden GEMM rebuilt as 128x128-tile m97 structure (16 MFMA/K-step/wave vs
//    8 in the old 128x64 tile; same 2 barriers + gl2lds staging) -> 256 blocks,
//    XCD-swizzled. Applied to gemm1/gemm2/gemm3/gemm4.
//  - dist stored as fp16 (order-preserving key only; candidates are fp64-refined
//    from condF). knn bisects on raw u16 bits (positive fp16 == integer order).
//    Halves gram write (67->33.5MB) and knn read; knn vals 64->32 VGPRs.
// Launch graph unchanged: 8 dispatches, knn/gemm1 hidden under MFMA kernels.
#include <hip/hip_runtime.h>
#include <hip/hip_fp16.h>
#include <stdint.h>

typedef unsigned short u16;
typedef unsigned int   u32;
typedef unsigned long long u64;
typedef short v8bf __attribute__((ext_vector_type(8)));
typedef float v4f  __attribute__((ext_vector_type(4)));
typedef u16   v8u  __attribute__((ext_vector_type(8)));

#define NPTS 4096
#define DF   128
#define DR   64
#define HID  1024
#define KNN  10
#define DIN  192

#define AS1 __attribute__((address_space(1)))
#define AS3 __attribute__((address_space(3)))

__device__ __forceinline__ float bf2f(u16 b){ return __uint_as_float(((unsigned)b)<<16); }
__device__ __forceinline__ u16 f2bf(float f){
  unsigned u = __float_as_uint(f);
  unsigned r = 0x7fffu + ((u>>16)&1u);
  return (u16)((u + r)>>16);
}
__device__ __forceinline__ u16 f2h(float f){
  __half h = __float2half(f);           // RN, monotone
  return __half_as_ushort(h);
}
__device__ __forceinline__ float softplus_f(float x){
  return x>15.f ? x : __logf(1.f + __expf(x));
}
__device__ __forceinline__ float rdv(const void* p, long j, int fl){
  return fl ? bf2f(((const u16*)p)[j]) : ((const float*)p)[j];
}
__device__ __forceinline__ void gl2lds16(const u16* g, u16* l){
  __builtin_amdgcn_global_load_lds((const AS1 unsigned int*)g, (AS3 unsigned int*)l, 16, 0, 0);
}

// ---------- dtype detection (R2-proven) ----------
__global__ void detect_k(const u16* __restrict__ c, int* __restrict__ flag){
  __shared__ int cnt[256];
  int t = threadIdx.x, n = 0;
  for(int i=t; i<8192; i+=256){
    u16 v = c[2*i];
    int e = (v>>7)&0xff;
    n += (e>=96 && e<=158);
  }
  cnt[t] = n; __syncthreads();
  for(int s=128; s>0; s>>=1){ if(t<s) cnt[t]+=cnt[t+s]; __syncthreads(); }
  if(t==0) *flag = (cnt[0] > 4915) ? 1 : 0;
}

// ---------- fused prep: cvt | weight transposes | sqnorm(raw) | buildx(raw) ----------
__global__ void prep_k(const void* cond, const void* tens,
    const void* Wi, const void* W1, const void* W2, const void* W3, const void* Wo,
    const void* bi, const void* b1, const void* b2, const void* b3, const void* bo,
    float* __restrict__ condF, float* __restrict__ tensF, float* __restrict__ biasF,
    u16* Oi, u16* O1, u16* O2, u16* O3, u16* Oo,
    float* __restrict__ sq, u16* __restrict__ X, const int* __restrict__ flag){
  __shared__ u16 tile[32][33];
  const int fl = *flag;
  const int bid = blockIdx.x, tid = threadIdx.x;
  if(bid < 3089){
    int i = bid*256 + tid;
    if(i < 524288){ condF[i] = rdv(cond, i, fl); }
    else if(i < 786432){ tensF[i-524288] = rdv(tens, i-524288, fl); }
    else{
      int j = i - 786432;
      if(j < 1024)      biasF[j] = rdv(bi, j, fl);
      else if(j < 2048) biasF[j] = rdv(b1, j-1024, fl);
      else if(j < 3072) biasF[j] = rdv(b2, j-2048, fl);
      else if(j < 4096) biasF[j] = rdv(b3, j-3072, fl);
      else if(j < 4160) biasF[j] = rdv(bo, j-4096, fl);
    }
  } else if(bid < 6417){
    int b = bid - 3089;
    const void* in; u16* out; int R, C, bx, by;
    if(b < 192)      {              in=Wi; out=Oi; R=192;  C=1024; bx=b&31; by=b>>5; }
    else if(b < 1216){ b -= 192;    in=W1; out=O1; R=1024; C=1024; bx=b&31; by=b>>5; }
    else if(b < 2240){ b -= 1216;   in=W2; out=O2; R=1024; C=1024; bx=b&31; by=b>>5; }
    else if(b < 3264){ b -= 2240;   in=W3; out=O3; R=1024; C=1024; bx=b&31; by=b>>5; }
    else             { b -= 3264;   in=Wo; out=Oo; R=1024; C=64;   bx=b&1;  by=b>>1; }
    int gx = bx*32, gy = by*32;
    int tx = tid&31, ty = tid>>5;
    #pragma unroll
    for(int r=ty; r<32; r+=8){
      size_t idx = (size_t)(gy+r)*C + gx + tx;
      tile[r][tx] = fl ? ((const u16*)in)[idx] : f2bf(((const float*)in)[idx]);
    }
    __syncthreads();
    #pragma unroll
    for(int r=ty; r<32; r+=8) out[(size_t)(gx+r)*R + gy + tx] = tile[tx][r];
  } else if(bid < 7441){
    int b = bid - 6417;
    int row = b*4 + (tid>>6), lane = tid&63;
    float a = rdv(cond, (long)row*DF + lane, fl);
    float c2 = rdv(cond, (long)row*DF + lane + 64, fl);
    double s = (double)a*a + (double)c2*c2;
    #pragma unroll
    for(int off=32; off>0; off>>=1) s += __shfl_down(s, off, 64);
    if(lane==0) sq[row] = (float)s;
  } else {
    int c = (bid-7441)*256 + tid;
    int j = c/48;
    int off = (c - j*48)*4;
    ushort4 o;
    if(off < DF){
      o.x = f2bf(rdv(cond, (long)j*DF + off + 0, fl));
      o.y = f2bf(rdv(cond, (long)j*DF + off + 1, fl));
      o.z = f2bf(rdv(cond, (long)j*DF + off + 2, fl));
      o.w = f2bf(rdv(cond, (long)j*DF + off + 3, fl));
    }else{
      int t2 = off - DF;
      o.x = f2bf(rdv(tens, (long)j*DR + t2 + 0, fl));
      o.y = f2bf(rdv(tens, (long)j*DR + t2 + 1, fl));
      o.z = f2bf(rdv(tens, (long)j*DR + t2 + 2, fl));
      o.w = f2bf(rdv(tens, (long)j*DR + t2 + 3, fl));
    }
    *(ushort4*)&X[(size_t)j*DIN + off] = o;
  }
}

// ---------- hidden-layer GEMM: 128x128 tile (m97 structure), softplus epilogue ----------
// 256 blocks, 4 waves, 4x4 acc/wave, 16 MFMA per K-step per wave, BK=32.
// XCD swizzle: each XCD gets 4 contiguous M-panels x all 8 N-panels.
__device__ __forceinline__ void gemm128_body(const u16* __restrict__ A,
    const u16* __restrict__ Bt, const float* __restrict__ bias, u16* __restrict__ C,
    int Kc, int bid, u16* As, u16* Bs){
  const int wg = (bid&7)*32 + (bid>>3);
  const int bm = (wg>>3)*128, bn = (wg&7)*128;
  const int lane = threadIdx.x&63, wave = threadIdx.x>>6;
  const int wm = (wave&1)*64, wn = (wave>>1)*64;
  const int sr = wave*32 + (lane>>2), sc = (lane&3)*8;
  const u16* pA0 = A  + (size_t)(bm+sr   )*Kc + sc;
  const u16* pA1 = A  + (size_t)(bm+sr+16)*Kc + sc;
  const u16* pB0 = Bt + (size_t)(bn+sr   )*Kc + sc;
  const u16* pB1 = Bt + (size_t)(bn+sr+16)*Kc + sc;
  u16* lA0 = &As[wave*1024];
  u16* lA1 = &As[wave*1024 + 512];
  u16* lB0 = &Bs[wave*1024];
  u16* lB1 = &Bs[wave*1024 + 512];
  const int m16 = lane&15, q = lane>>4;
  v4f acc[4][4] = {};
  for(int kb=0; kb<Kc; kb+=32){
    gl2lds16(pA0 + kb, lA0);
    gl2lds16(pA1 + kb, lA1);
    gl2lds16(pB0 + kb, lB0);
    gl2lds16(pB1 + kb, lB1);
    __syncthreads();
    v8bf a[4], b[4];
    #pragma unroll
    for(int x=0;x<4;x++){
      a[x] = *(const v8bf*)&As[(wm + x*16 + m16)*32 + q*8];
      b[x] = *(const v8bf*)&Bs[(wn + x*16 + m16)*32 + q*8];
    }
    #pragma unroll
    for(int mi=0;mi<4;mi++)
      #pragma unroll
      for(int ni=0;ni<4;ni++)
        acc[mi][ni] = __builtin_amdgcn_mfma_f32_16x16x32_bf16(a[mi], b[ni], acc[mi][ni], 0,0,0);
    __syncthreads();
  }
  const int col16 = lane&15, rowq = lane>>4;
  #pragma unroll
  for(int mi=0;mi<4;mi++){
    #pragma unroll
    for(int ni=0;ni<4;ni++){
      int cn = bn + wn + ni*16 + col16;
      float bi = bias[cn];
      #pragma unroll
      for(int r=0;r<4;r++){
        int rw = bm + wm + mi*16 + rowq*4 + r;
        float v = softplus_f(acc[mi][ni][r] + bi);
        C[(size_t)rw*HID + cn] = f2bf(v);
      }
    }
  }
}

// ---------- knn body: one wave per row, fp16-key bisection on u16 bits ----------
// Positive fp16: integer order == float order. Monotone RN rounding guarantees
// exact top-10 subset of {q(d) < t} when count(<t) >= 16. fp64 refine from condF.
__device__ __forceinline__ void knn_body(const u16* __restrict__ distH,
    const float* __restrict__ condF, int* __restrict__ nidx, int row,
    float* __restrict__ af, int* __restrict__ scnt,
    int* __restrict__ cand, u64* __restrict__ keys){
  const int lane = threadIdx.x&63;
  af[lane]    = condF[(size_t)row*DF + lane];
  af[lane+64] = condF[(size_t)row*DF + lane + 64];
  if(lane==0) *scnt = 0;
  const v8u* drow = (const v8u*)(distH + (size_t)row*NPTS);
  v8u vals[8];
  #pragma unroll
  for(int k=0;k<8;k++) vals[k] = drow[lane + k*64];
  u32 mx = 0;
  #pragma unroll
  for(int k=0;k<8;k++)
    #pragma unroll
    for(int e=0;e<8;e++){ u32 v = vals[k][e]; mx = v>mx ? v : mx; }
  #pragma unroll
  for(int off=32; off>0; off>>=1){
    u32 o = (u32)__shfl_down((int)mx, off, 64); mx = o>mx ? o : mx;
  }
  mx = (u32)__shfl((int)mx, 0, 64);
  u32 hi = mx+1, lo = 0;
  for(int it=0; it<17; ++it){
    u32 mid = (lo+hi)>>1;
    int c = 0;
    #pragma unroll
    for(int k=0;k<8;k++)
      #pragma unroll
      for(int e=0;e<8;e++) c += ((u32)vals[k][e] < mid);
    #pragma unroll
    for(int off=32; off>0; off>>=1) c += __shfl_down(c, off, 64);
    c = __shfl(c, 0, 64);
    if(c >= 16){ hi = mid; if(c <= 48) break; }
    else lo = mid;
  }
  const u32 t = hi;
  #pragma unroll
  for(int k=0;k<8;k++)
    #pragma unroll
    for(int e=0;e<8;e++){
      if((u32)vals[k][e] < t){
        int s = atomicAdd(scnt, 1);
        if(s < 64) cand[s] = (lane + k*64)*8 + e;
      }
    }
  // same-wave LDS ordering: all atomics precede this read in program order.
  int cnt = *scnt; if(cnt > 64) cnt = 64;
  u64 mykey = ~0ULL; int myj = -1;
  if(lane < cnt){
    int j = cand[lane];
    const float4* bp4 = (const float4*)(condF + (size_t)j*DF);
    double s = 0.0;
    #pragma unroll
    for(int v4i=0; v4i<32; v4i++){
      float4 bv = bp4[v4i];
      double d0 = (double)af[v4i*4+0]-(double)bv.x;
      double d1 = (double)af[v4i*4+1]-(double)bv.y;
      double d2 = (double)af[v4i*4+2]-(double)bv.z;
      double d3 = (double)af[v4i*4+3]-(double)bv.w;
      s += d0*d0 + d1*d1 + d2*d2 + d3*d3;
    }
    u64 bits = (u64)__double_as_longlong(s);
    mykey = (bits & ~0xFFFULL) | (u32)j;
    myj = j;
  }
  keys[lane] = mykey;
  if(lane < cnt){
    int rank = 0;
    for(int c2=0;c2<cnt;c2++) rank += (keys[c2] < mykey);
    if(rank < KNN) nidx[row*KNN + rank] = myj;
  }
}

// ---------- fused: gemm1 (blocks 0..255, K=192) || gram->fp16 d^2 (blocks 256..1279) ----------
// LDS unioned: gram 40KB, gemm 16KB -> 40KB total (2 blocks/CU fits).
__global__ __launch_bounds__(256,2) void gram_g1_k(const u16* __restrict__ condB,
    const float* __restrict__ condF, const float* __restrict__ sq,
    u16* __restrict__ distH, const int* __restrict__ flag,
    const u16* __restrict__ X, const u16* __restrict__ Wt_in,
    const float* __restrict__ biasF, u16* __restrict__ A0){
  __shared__ __align__(16) u16 smem[20480];
  const int bid = blockIdx.x;
  if(bid < 256){
    gemm128_body(X, Wt_in, biasF, A0, DIN, bid, smem, smem+4096);
    return;
  }
  const int gb = bid - 256;
  u16* Ahi = smem;
  u16* Alo = smem + 5120;
  u16* Bhi = smem + 10240;
  u16* Blo = smem + 15360;
  const int fl = *flag;
  const int bm = (gb&31)*128, bn = (gb>>5)*128;
  const int tid = threadIdx.x, lane = tid&63, wave = tid>>6;
  const int wm = (wave&1)*64, wn = (wave>>1)*64;
  v4f acc[4][4] = {};
  for(int kb=0; kb<DF; kb+=32){
    if(fl){
      #pragma unroll
      for(int t=0;t<2;t++){
        int c2 = tid + t*256;
        int r = c2>>2, col = (c2&3)*8;
        *(uint4*)&Ahi[r*40+col] = *(const uint4*)&condB[(size_t)(bm+r)*DF + kb + col];
        *(uint4*)&Bhi[r*40+col] = *(const uint4*)&condB[(size_t)(bn+r)*DF + kb + col];
      }
    }else{
      #pragma unroll
      for(int t=0;t<4;t++){
        int ch = tid + t*256;
        int r = ch>>3, c = (ch&7)*4;
        float4 av = *(const float4*)&condF[(size_t)(bm+r)*DF + kb + c];
        float4 bv = *(const float4*)&condF[(size_t)(bn+r)*DF + kb + c];
        ushort4 ah, bh, al, bl;
        ah.x=f2bf(av.x); ah.y=f2bf(av.y); ah.z=f2bf(av.z); ah.w=f2bf(av.w);
        bh.x=f2bf(bv.x); bh.y=f2bf(bv.y); bh.z=f2bf(bv.z); bh.w=f2bf(bv.w);
        al.x=f2bf(av.x-bf2f(ah.x)); al.y=f2bf(av.y-bf2f(ah.y));
        al.z=f2bf(av.z-bf2f(ah.z)); al.w=f2bf(av.w-bf2f(ah.w));
        bl.x=f2bf(bv.x-bf2f(bh.x)); bl.y=f2bf(bv.y-bf2f(bh.y));
        bl.z=f2bf(bv.z-bf2f(bh.z)); bl.w=f2bf(bv.w-bf2f(bh.w));
        *(ushort4*)&Ahi[r*40+c] = ah; *(ushort4*)&Bhi[r*40+c] = bh;
        *(ushort4*)&Alo[r*40+c] = al; *(ushort4*)&Blo[r*40+c] = bl;
      }
    }
    __syncthreads();
    const int m16 = lane&15, q = lane>>4;
    v8bf ahf[4], bhf[4];
    #pragma unroll
    for(int x=0;x<4;x++){
      ahf[x] = *(const v8bf*)&Ahi[(wm + x*16 + m16)*40 + q*8];
      bhf[x] = *(const v8bf*)&Bhi[(wn + x*16 + m16)*40 + q*8];
    }
    if(!fl){
      v8bf alf[4], blf[4];
      #pragma unroll
      for(int x=0;x<4;x++){
        alf[x] = *(const v8bf*)&Alo[(wm + x*16 + m16)*40 + q*8];
        blf[x] = *(const v8bf*)&Blo[(wn + x*16 + m16)*40 + q*8];
      }
      #pragma unroll
      for(int mi=0;mi<4;mi++)
        #pragma unroll
        for(int ni=0;ni<4;ni++){
          acc[mi][ni] = __builtin_amdgcn_mfma_f32_16x16x32_bf16(alf[mi], bhf[ni], acc[mi][ni], 0,0,0);
          acc[mi][ni] = __builtin_amdgcn_mfma_f32_16x16x32_bf16(ahf[mi], blf[ni], acc[mi][ni], 0,0,0);
        }
    }
    #pragma unroll
    for(int mi=0;mi<4;mi++)
      #pragma unroll
      for(int ni=0;ni<4;ni++)
        acc[mi][ni] = __builtin_amdgcn_mfma_f32_16x16x32_bf16(ahf[mi], bhf[ni], acc[mi][ni], 0,0,0);
    __syncthreads();
  }
  const int col16 = lane&15, rowq = lane>>4;
  #pragma unroll
  for(int mi=0;mi<4;mi++){
    #pragma unroll
    for(int ni=0;ni<4;ni++){
      int cj = bn + wn + ni*16 + col16;
      float sqj = sq[cj];
      #pragma unroll
      for(int r=0;r<4;r++){
        int ri = bm + wm + mi*16 + rowq*4 + r;
        float d2 = (sq[ri] + sqj) - 2.0f*acc[mi][ni][r];
        distH[(size_t)ri*NPTS + cj] = f2h(fmaxf(d2, 0.f));
      }
    }
  }
}

// ---------- fused: hidden GEMM (blocks 0..255) || knn half (blocks 256..767) ----------
__global__ __launch_bounds__(256,2) void gemm_knn_k(const u16* __restrict__ A,
    const u16* __restrict__ Bt, const float* __restrict__ bias, u16* __restrict__ C,
    const u16* __restrict__ distH, const float* __restrict__ condF,
    int* __restrict__ nidx, int rowoff){
  __shared__ __align__(16) u16 gsm[8192];
  __shared__ float af[4][DF];
  __shared__ int   scnt[4];
  __shared__ int   cand[4][64];
  __shared__ u64   keys[4][64];
  const int bid = blockIdx.x;
  if(bid < 256){
    gemm128_body(A, Bt, bias, C, HID, bid, gsm, gsm+4096);
  } else {
    const int wv = threadIdx.x>>6;
    const int row = rowoff + (bid-256)*4 + wv;
    knn_body(distH, condF, nidx, row, af[wv], &scnt[wv], cand[wv], keys[wv]);
  }
}

// ---------- standalone hidden GEMM (layer 4) ----------
__global__ __launch_bounds__(256,2) void gemm_bt_k(const u16* __restrict__ A,
    const u16* __restrict__ Bt, const float* __restrict__ bias, u16* __restrict__ C){
  __shared__ __align__(16) u16 As[4096];
  __shared__ __align__(16) u16 Bs[4096];
  gemm128_body(A, Bt, bias, C, HID, blockIdx.x, As, Bs);
}

// ---------- final layer, split-K=4: Pp[s][r][c] = partial A@Wout^T ----------
__global__ __launch_bounds__(256,2) void gemm_out_k(const u16* __restrict__ A,
    const u16* __restrict__ Bt, float* __restrict__ Pp){
  __shared__ __align__(16) u16 As[128*32];
  __shared__ __align__(16) u16 Bs[64*32];
  const int bm = (blockIdx.x>>2)*128;
  const int k0 = (blockIdx.x&3)*256;
  float* P = Pp + (size_t)(blockIdx.x&3)*262144;
  const int tid = threadIdx.x, lane = tid&63, wave = tid>>6;
  const int wm = wave*32;
  int c0 = wave*128 + lane, c1 = c0 + 64;
  int ra0 = c0>>2, qa0 = c0&3, ra1 = c1>>2, qa1 = c1&3;
  int cb = wave*64 + lane;
  int rb = cb>>2, qb = cb&3;
  const u16* pA0 = A  + (size_t)(bm+ra0)*HID + qa0*8;
  const u16* pA1 = A  + (size_t)(bm+ra1)*HID + qa1*8;
  const u16* pB  = Bt + (size_t)rb*HID + qb*8;
  u16* lA0 = &As[(wave*128     )*8];
  u16* lA1 = &As[(wave*128 + 64)*8];
  u16* lB  = &Bs[(wave*64      )*8];
  const int m16 = lane&15, q = lane>>4;
  v4f acc[2][4] = {};
  for(int kb=k0; kb<k0+256; kb+=32){
    gl2lds16(pA0 + kb, lA0);
    gl2lds16(pA1 + kb, lA1);
    gl2lds16(pB  + kb, lB);
    __syncthreads();
    v8bf a[2], b[4];
    a[0] = *(const v8bf*)&As[(wm + m16)*32 + q*8];
    a[1] = *(const v8bf*)&As[(wm + 16 + m16)*32 + q*8];
    #pragma unroll
    for(int x=0;x<4;x++) b[x] = *(const v8bf*)&Bs[(x*16 + m16)*32 + q*8];
    #pragma unroll
    for(int mi=0;mi<2;mi++)
      #pragma unroll
      for(int ni=0;ni<4;ni++)
        acc[mi][ni] = __builtin_amdgcn_mfma_f32_16x16x32_bf16(a[mi], b[ni], acc[mi][ni], 0,0,0);
    __syncthreads();
  }
  const int col16 = lane&15, rowq = lane>>4;
  #pragma unroll
  for(int mi=0;mi<2;mi++){
    #pragma unroll
    for(int ni=0;ni<4;ni++){
      int cn = ni*16 + col16;
      #pragma unroll
      for(int r=0;r<4;r++){
        int rw = bm + wm + mi*16 + rowq*4 + r;
        P[(size_t)rw*DR + cn] = acc[mi][ni][r];
      }
    }
  }
}

// ---------- gather: out[i,k,:] = tens[j] - (bias + sum_s Pp[s][j]), j=nidx ----------
__global__ void gather_k(const float* __restrict__ Pp, const float* __restrict__ tensF,
                         const float* __restrict__ biasF, const int* __restrict__ nidx,
                         void* __restrict__ outv, const int* __restrict__ flag){
  const int fl = *flag;
  int e = blockIdx.x*256 + threadIdx.x;
  int m = e>>4;
  int c = (e&15)*4;
  int j = nidx[m] & (NPTS-1);
  size_t rc = (size_t)j*DR + c;
  float4 t  = *(const float4*)&tensF[rc];
  float4 b  = *(const float4*)&biasF[4096 + c];
  float4 p0 = *(const float4*)&Pp[rc];
  float4 p1 = *(const float4*)&Pp[262144 + rc];
  float4 p2 = *(const float4*)&Pp[524288 + rc];
  float4 p3 = *(const float4*)&Pp[786432 + rc];
  float4 v;
  v.x = t.x - (b.x + ((p0.x+p1.x)+(p2.x+p3.x)));
  v.y = t.y - (b.y + ((p0.y+p1.y)+(p2.y+p3.y)));
  v.z = t.z - (b.z + ((p0.z+p1.z)+(p2.z+p3.z)));
  v.w = t.w - (b.w + ((p0.w+p1.w)+(p2.w+p3.w)));
  if(fl){
    ushort4 o; o.x=f2bf(v.x); o.y=f2bf(v.y); o.z=f2bf(v.z); o.w=f2bf(v.w);
    *(ushort4*)&((u16*)outv)[(size_t)m*DR + c] = o;
  }else{
    *(float4*)&((float*)outv)[(size_t)m*DR + c] = v;
  }
}

// ---------- workspace layout (~68 MB of 256 MiB; no aliasing) ----------
constexpr size_t OFF_FLAG  = 0;
constexpr size_t OFF_SQ    = 256;
constexpr size_t OFF_NIDX  = OFF_SQ    + 16384;
constexpr size_t OFF_BIAS  = OFF_NIDX  + 163840;
constexpr size_t OFF_CONDF = OFF_BIAS  + 16640;
constexpr size_t OFF_TENSF = OFF_CONDF + 2097152;
constexpr size_t OFF_WTIN  = OFF_TENSF + 1048576;
constexpr size_t OFF_WT1   = OFF_WTIN  + 393216;
constexpr size_t OFF_WT2   = OFF_WT1   + 2097152;
constexpr size_t OFF_WT3   = OFF_WT2   + 2097152;
constexpr size_t OFF_WTO   = OFF_WT3   + 2097152;
constexpr size_t OFF_DIST  = OFF_WTO   + 131072;
constexpr size_t OFF_X     = OFF_DIST  + 33554432;   // fp16 dist
constexpr size_t OFF_A0    = OFF_X     + 1572864;
constexpr size_t OFF_A1    = OFF_A0    + 8388608;
constexpr size_t OFF_P     = OFF_A1    + 8388608;    // 4 x 1MB partials

extern "C" void kernel_launch(void* const* d_in, const int* in_sizes, int n_in,
                              void* d_out, int out_size, void* d_ws, size_t ws_size,
                              hipStream_t stream){
  char* ws = (char*)d_ws;
  int*   flag  = (int*)  (ws + OFF_FLAG);
  float* sqv   = (float*)(ws + OFF_SQ);
  int*   nidx  = (int*)  (ws + OFF_NIDX);
  float* biasF = (float*)(ws + OFF_BIAS);
  float* condF = (float*)(ws + OFF_CONDF);
  float* tensF = (float*)(ws + OFF_TENSF);
  u16*   Wt_in = (u16*)  (ws + OFF_WTIN);
  u16*   Wt1   = (u16*)  (ws + OFF_WT1);
  u16*   Wt2   = (u16*)  (ws + OFF_WT2);
  u16*   Wt3   = (u16*)  (ws + OFF_WT3);
  u16*   Wt_o  = (u16*)  (ws + OFF_WTO);
  u16*   distH = (u16*)  (ws + OFF_DIST);
  u16*   X     = (u16*)  (ws + OFF_X);
  u16*   A0    = (u16*)  (ws + OFF_A0);
  u16*   A1    = (u16*)  (ws + OFF_A1);
  float* Pp    = (float*)(ws + OFF_P);

  detect_k <<<1, 256, 0, stream>>>((const u16*)d_in[0], flag);
  prep_k   <<<8209, 256, 0, stream>>>(d_in[0], d_in[1],
                d_in[2], d_in[4], d_in[6], d_in[8], d_in[10],
                d_in[3], d_in[5], d_in[7], d_in[9], d_in[11],
                condF, tensF, biasF, Wt_in, Wt1, Wt2, Wt3, Wt_o, sqv, X, flag);
  // gemm1 || gram  (both depend only on prep)
  gram_g1_k<<<1280, 256, 0, stream>>>((const u16*)d_in[0], condF, sqv, distH, flag,
                                      X, Wt_in, biasF, A0);
  // gemm2 || knn rows 0..2047
  gemm_knn_k<<<768, 256, 0, stream>>>(A0, Wt1, biasF+1024, A1, distH, condF, nidx, 0);
  // gemm3 || knn rows 2048..4095
  gemm_knn_k<<<768, 256, 0, stream>>>(A1, Wt2, biasF+2048, A0, distH, condF, nidx, 2048);
  gemm_bt_k  <<<256, 256, 0, stream>>>(A0, Wt3, biasF+3072, A1);
  gemm_out_k <<<128, 256, 0, stream>>>(A1, Wt_o, Pp);
  gather_k   <<<2560, 256, 0, stream>>>(Pp, tensF, biasF, nidx, d_out, flag);
}

// Round 3
// 209.613 us; speedup vs baseline: 1.0567x; 1.0567x over previous
//
// MongeGapTransport: KNN gather + 5-layer MLP pushforward, bf16 I/O (confirmed).
// R18: post-mortem of R17 (221.5us, regressed from 214.6):
//  - 128x128 tile gave 256 blocks = 1 block/CU = 1 wave/SIMD; barrier drains
//    fully exposed (~12us/GEMM). Occupancy >= 2 blocks/CU is binding.
//  - fp16 dist lever worked (kept).
// R18 GEMM: 128x64 tile (512 blocks, 2/CU as R16-proven) + BK=64: 6 gl2lds
// stage both K-halves, then 16 MFMA per barrier pair (2x R16 density at
// R16 occupancy). LDS 24KB/block. Applied to gemm1/2/3/4.
#include <hip/hip_runtime.h>
#include <hip/hip_fp16.h>
#include <stdint.h>

typedef unsigned short u16;
typedef unsigned int   u32;
typedef unsigned long long u64;
typedef short v8bf __attribute__((ext_vector_type(8)));
typedef float v4f  __attribute__((ext_vector_type(4)));
typedef u16   v8u  __attribute__((ext_vector_type(8)));

#define NPTS 4096
#define DF   128
#define DR   64
#define HID  1024
#define KNN  10
#define DIN  192

#define AS1 __attribute__((address_space(1)))
#define AS3 __attribute__((address_space(3)))

__device__ __forceinline__ float bf2f(u16 b){ return __uint_as_float(((unsigned)b)<<16); }
__device__ __forceinline__ u16 f2bf(float f){
  unsigned u = __float_as_uint(f);
  unsigned r = 0x7fffu + ((u>>16)&1u);
  return (u16)((u + r)>>16);
}
__device__ __forceinline__ u16 f2h(float f){
  __half h = __float2half(f);           // RN, monotone
  return __half_as_ushort(h);
}
__device__ __forceinline__ float softplus_f(float x){
  return x>15.f ? x : __logf(1.f + __expf(x));
}
__device__ __forceinline__ float rdv(const void* p, long j, int fl){
  return fl ? bf2f(((const u16*)p)[j]) : ((const float*)p)[j];
}
__device__ __forceinline__ void gl2lds16(const u16* g, u16* l){
  __builtin_amdgcn_global_load_lds((const AS1 unsigned int*)g, (AS3 unsigned int*)l, 16, 0, 0);
}

// ---------- dtype detection (R2-proven) ----------
__global__ void detect_k(const u16* __restrict__ c, int* __restrict__ flag){
  __shared__ int cnt[256];
  int t = threadIdx.x, n = 0;
  for(int i=t; i<8192; i+=256){
    u16 v = c[2*i];
    int e = (v>>7)&0xff;
    n += (e>=96 && e<=158);
  }
  cnt[t] = n; __syncthreads();
  for(int s=128; s>0; s>>=1){ if(t<s) cnt[t]+=cnt[t+s]; __syncthreads(); }
  if(t==0) *flag = (cnt[0] > 4915) ? 1 : 0;
}

// ---------- fused prep: cvt | weight transposes | sqnorm(raw) | buildx(raw) ----------
__global__ void prep_k(const void* cond, const void* tens,
    const void* Wi, const void* W1, const void* W2, const void* W3, const void* Wo,
    const void* bi, const void* b1, const void* b2, const void* b3, const void* bo,
    float* __restrict__ condF, float* __restrict__ tensF, float* __restrict__ biasF,
    u16* Oi, u16* O1, u16* O2, u16* O3, u16* Oo,
    float* __restrict__ sq, u16* __restrict__ X, const int* __restrict__ flag){
  __shared__ u16 tile[32][33];
  const int fl = *flag;
  const int bid = blockIdx.x, tid = threadIdx.x;
  if(bid < 3089){
    int i = bid*256 + tid;
    if(i < 524288){ condF[i] = rdv(cond, i, fl); }
    else if(i < 786432){ tensF[i-524288] = rdv(tens, i-524288, fl); }
    else{
      int j = i - 786432;
      if(j < 1024)      biasF[j] = rdv(bi, j, fl);
      else if(j < 2048) biasF[j] = rdv(b1, j-1024, fl);
      else if(j < 3072) biasF[j] = rdv(b2, j-2048, fl);
      else if(j < 4096) biasF[j] = rdv(b3, j-3072, fl);
      else if(j < 4160) biasF[j] = rdv(bo, j-4096, fl);
    }
  } else if(bid < 6417){
    int b = bid - 3089;
    const void* in; u16* out; int R, C, bx, by;
    if(b < 192)      {              in=Wi; out=Oi; R=192;  C=1024; bx=b&31; by=b>>5; }
    else if(b < 1216){ b -= 192;    in=W1; out=O1; R=1024; C=1024; bx=b&31; by=b>>5; }
    else if(b < 2240){ b -= 1216;   in=W2; out=O2; R=1024; C=1024; bx=b&31; by=b>>5; }
    else if(b < 3264){ b -= 2240;   in=W3; out=O3; R=1024; C=1024; bx=b&31; by=b>>5; }
    else             { b -= 3264;   in=Wo; out=Oo; R=1024; C=64;   bx=b&1;  by=b>>1; }
    int gx = bx*32, gy = by*32;
    int tx = tid&31, ty = tid>>5;
    #pragma unroll
    for(int r=ty; r<32; r+=8){
      size_t idx = (size_t)(gy+r)*C + gx + tx;
      tile[r][tx] = fl ? ((const u16*)in)[idx] : f2bf(((const float*)in)[idx]);
    }
    __syncthreads();
    #pragma unroll
    for(int r=ty; r<32; r+=8) out[(size_t)(gx+r)*R + gy + tx] = tile[tx][r];
  } else if(bid < 7441){
    int b = bid - 6417;
    int row = b*4 + (tid>>6), lane = tid&63;
    float a = rdv(cond, (long)row*DF + lane, fl);
    float c2 = rdv(cond, (long)row*DF + lane + 64, fl);
    double s = (double)a*a + (double)c2*c2;
    #pragma unroll
    for(int off=32; off>0; off>>=1) s += __shfl_down(s, off, 64);
    if(lane==0) sq[row] = (float)s;
  } else {
    int c = (bid-7441)*256 + tid;
    int j = c/48;
    int off = (c - j*48)*4;
    ushort4 o;
    if(off < DF){
      o.x = f2bf(rdv(cond, (long)j*DF + off + 0, fl));
      o.y = f2bf(rdv(cond, (long)j*DF + off + 1, fl));
      o.z = f2bf(rdv(cond, (long)j*DF + off + 2, fl));
      o.w = f2bf(rdv(cond, (long)j*DF + off + 3, fl));
    }else{
      int t2 = off - DF;
      o.x = f2bf(rdv(tens, (long)j*DR + t2 + 0, fl));
      o.y = f2bf(rdv(tens, (long)j*DR + t2 + 1, fl));
      o.z = f2bf(rdv(tens, (long)j*DR + t2 + 2, fl));
      o.w = f2bf(rdv(tens, (long)j*DR + t2 + 3, fl));
    }
    *(ushort4*)&X[(size_t)j*DIN + off] = o;
  }
}

// ---------- hidden-layer GEMM body: 128x64 tile, BK=64, softplus epilogue ----------
// 512 blocks (2/CU), 16 MFMA per barrier pair per wave. LDS: As 16KB + Bs 8KB.
// As = two [128][32] half-tiles (K-halves), Bs = two [64][32] half-tiles.
__device__ __forceinline__ void gemm_bt_body(const u16* __restrict__ A,
    const u16* __restrict__ Bt, const float* __restrict__ bias, u16* __restrict__ C,
    int Nc, int Kc, int bid, u16* As, u16* Bs){
  const int xcd = bid&7, slot = bid>>3;
  const int bm = (xcd*4 + (slot>>4)) * 128;
  const int bn = (slot&15) * 64;
  const int tid = threadIdx.x, lane = tid&63, wave = tid>>6;
  const int wm = (wave&1)*64, wn = (wave>>1)*32;
  int c0 = wave*128 + lane, c1 = c0 + 64;
  int r0 = c0>>2, q0 = c0&3, r1 = c1>>2, q1 = c1&3;
  int cb = wave*64 + lane, rb = cb>>2, qb = cb&3;
  const u16* pA0 = A  + (size_t)(bm+r0)*Kc + q0*8;
  const u16* pA1 = A  + (size_t)(bm+r1)*Kc + q1*8;
  const u16* pB  = Bt + (size_t)(bn+rb)*Kc + qb*8;
  u16* lA0 = &As[wave*1024];
  u16* lA1 = &As[wave*1024 + 512];
  u16* lB  = &Bs[wave*512];
  const int m16 = lane&15, q = lane>>4;
  v4f acc[4][2] = {};
  for(int kb=0; kb<Kc; kb+=64){
    gl2lds16(pA0 + kb, lA0);
    gl2lds16(pA1 + kb, lA1);
    gl2lds16(pB  + kb, lB);
    gl2lds16(pA0 + kb + 32, lA0 + 4096);
    gl2lds16(pA1 + kb + 32, lA1 + 4096);
    gl2lds16(pB  + kb + 32, lB + 2048);
    __syncthreads();
    #pragma unroll
    for(int kk=0;kk<2;kk++){
      v8bf a[4], b[2];
      #pragma unroll
      for(int x=0;x<4;x++) a[x] = *(const v8bf*)&As[kk*4096 + (wm + x*16 + m16)*32 + q*8];
      #pragma unroll
      for(int x=0;x<2;x++) b[x] = *(const v8bf*)&Bs[kk*2048 + (wn + x*16 + m16)*32 + q*8];
      #pragma unroll
      for(int mi=0;mi<4;mi++)
        #pragma unroll
        for(int ni=0;ni<2;ni++)
          acc[mi][ni] = __builtin_amdgcn_mfma_f32_16x16x32_bf16(a[mi], b[ni], acc[mi][ni], 0,0,0);
    }
    __syncthreads();
  }
  const int col16 = lane&15, rowq = lane>>4;
  #pragma unroll
  for(int mi=0;mi<4;mi++){
    #pragma unroll
    for(int ni=0;ni<2;ni++){
      int cn = bn + wn + ni*16 + col16;
      float bi = bias[cn];
      #pragma unroll
      for(int r=0;r<4;r++){
        int rw = bm + wm + mi*16 + rowq*4 + r;
        float v = softplus_f(acc[mi][ni][r] + bi);
        C[(size_t)rw*Nc + cn] = f2bf(v);
      }
    }
  }
}

// ---------- knn body: one wave per row, fp16-key bisection on u16 bits ----------
__device__ __forceinline__ void knn_body(const u16* __restrict__ distH,
    const float* __restrict__ condF, int* __restrict__ nidx, int row,
    float* __restrict__ af, int* __restrict__ scnt,
    int* __restrict__ cand, u64* __restrict__ keys){
  const int lane = threadIdx.x&63;
  af[lane]    = condF[(size_t)row*DF + lane];
  af[lane+64] = condF[(size_t)row*DF + lane + 64];
  if(lane==0) *scnt = 0;
  const v8u* drow = (const v8u*)(distH + (size_t)row*NPTS);
  v8u vals[8];
  #pragma unroll
  for(int k=0;k<8;k++) vals[k] = drow[lane + k*64];
  u32 mx = 0;
  #pragma unroll
  for(int k=0;k<8;k++)
    #pragma unroll
    for(int e=0;e<8;e++){ u32 v = vals[k][e]; mx = v>mx ? v : mx; }
  #pragma unroll
  for(int off=32; off>0; off>>=1){
    u32 o = (u32)__shfl_down((int)mx, off, 64); mx = o>mx ? o : mx;
  }
  mx = (u32)__shfl((int)mx, 0, 64);
  u32 hi = mx+1, lo = 0;
  for(int it=0; it<17; ++it){
    u32 mid = (lo+hi)>>1;
    int c = 0;
    #pragma unroll
    for(int k=0;k<8;k++)
      #pragma unroll
      for(int e=0;e<8;e++) c += ((u32)vals[k][e] < mid);
    #pragma unroll
    for(int off=32; off>0; off>>=1) c += __shfl_down(c, off, 64);
    c = __shfl(c, 0, 64);
    if(c >= 16){ hi = mid; if(c <= 48) break; }
    else lo = mid;
  }
  const u32 t = hi;
  #pragma unroll
  for(int k=0;k<8;k++)
    #pragma unroll
    for(int e=0;e<8;e++){
      if((u32)vals[k][e] < t){
        int s = atomicAdd(scnt, 1);
        if(s < 64) cand[s] = (lane + k*64)*8 + e;
      }
    }
  // same-wave LDS ordering: all atomics precede this read in program order.
  int cnt = *scnt; if(cnt > 64) cnt = 64;
  u64 mykey = ~0ULL; int myj = -1;
  if(lane < cnt){
    int j = cand[lane];
    const float4* bp4 = (const float4*)(condF + (size_t)j*DF);
    double s = 0.0;
    #pragma unroll
    for(int v4i=0; v4i<32; v4i++){
      float4 bv = bp4[v4i];
      double d0 = (double)af[v4i*4+0]-(double)bv.x;
      double d1 = (double)af[v4i*4+1]-(double)bv.y;
      double d2 = (double)af[v4i*4+2]-(double)bv.z;
      double d3 = (double)af[v4i*4+3]-(double)bv.w;
      s += d0*d0 + d1*d1 + d2*d2 + d3*d3;
    }
    u64 bits = (u64)__double_as_longlong(s);
    mykey = (bits & ~0xFFFULL) | (u32)j;
    myj = j;
  }
  keys[lane] = mykey;
  if(lane < cnt){
    int rank = 0;
    for(int c2=0;c2<cnt;c2++) rank += (keys[c2] < mykey);
    if(rank < KNN) nidx[row*KNN + rank] = myj;
  }
}

// ---------- fused: gemm1 (blocks 0..511, K=192) || gram->fp16 d^2 (blocks 512..1535) ----------
// LDS unioned: gram 40KB, gemm 24KB -> 40KB total (2 blocks/CU fits).
__global__ __launch_bounds__(256,2) void gram_g1_k(const u16* __restrict__ condB,
    const float* __restrict__ condF, const float* __restrict__ sq,
    u16* __restrict__ distH, const int* __restrict__ flag,
    const u16* __restrict__ X, const u16* __restrict__ Wt_in,
    const float* __restrict__ biasF, u16* __restrict__ A0){
  __shared__ __align__(16) u16 smem[20480];
  const int bid = blockIdx.x;
  if(bid < 512){
    gemm_bt_body(X, Wt_in, biasF, A0, HID, DIN, bid, smem, smem+8192);
    return;
  }
  const int gb = bid - 512;
  u16* Ahi = smem;
  u16* Alo = smem + 5120;
  u16* Bhi = smem + 10240;
  u16* Blo = smem + 15360;
  const int fl = *flag;
  const int bm = (gb&31)*128, bn = (gb>>5)*128;
  const int tid = threadIdx.x, lane = tid&63, wave = tid>>6;
  const int wm = (wave&1)*64, wn = (wave>>1)*64;
  v4f acc[4][4] = {};
  for(int kb=0; kb<DF; kb+=32){
    if(fl){
      #pragma unroll
      for(int t=0;t<2;t++){
        int c2 = tid + t*256;
        int r = c2>>2, col = (c2&3)*8;
        *(uint4*)&Ahi[r*40+col] = *(const uint4*)&condB[(size_t)(bm+r)*DF + kb + col];
        *(uint4*)&Bhi[r*40+col] = *(const uint4*)&condB[(size_t)(bn+r)*DF + kb + col];
      }
    }else{
      #pragma unroll
      for(int t=0;t<4;t++){
        int ch = tid + t*256;
        int r = ch>>3, c = (ch&7)*4;
        float4 av = *(const float4*)&condF[(size_t)(bm+r)*DF + kb + c];
        float4 bv = *(const float4*)&condF[(size_t)(bn+r)*DF + kb + c];
        ushort4 ah, bh, al, bl;
        ah.x=f2bf(av.x); ah.y=f2bf(av.y); ah.z=f2bf(av.z); ah.w=f2bf(av.w);
        bh.x=f2bf(bv.x); bh.y=f2bf(bv.y); bh.z=f2bf(bv.z); bh.w=f2bf(bv.w);
        al.x=f2bf(av.x-bf2f(ah.x)); al.y=f2bf(av.y-bf2f(ah.y));
        al.z=f2bf(av.z-bf2f(ah.z)); al.w=f2bf(av.w-bf2f(ah.w));
        bl.x=f2bf(bv.x-bf2f(bh.x)); bl.y=f2bf(bv.y-bf2f(bh.y));
        bl.z=f2bf(bv.z-bf2f(bh.z)); bl.w=f2bf(bv.w-bf2f(bh.w));
        *(ushort4*)&Ahi[r*40+c] = ah; *(ushort4*)&Bhi[r*40+c] = bh;
        *(ushort4*)&Alo[r*40+c] = al; *(ushort4*)&Blo[r*40+c] = bl;
      }
    }
    __syncthreads();
    const int m16 = lane&15, q = lane>>4;
    v8bf ahf[4], bhf[4];
    #pragma unroll
    for(int x=0;x<4;x++){
      ahf[x] = *(const v8bf*)&Ahi[(wm + x*16 + m16)*40 + q*8];
      bhf[x] = *(const v8bf*)&Bhi[(wn + x*16 + m16)*40 + q*8];
    }
    if(!fl){
      v8bf alf[4], blf[4];
      #pragma unroll
      for(int x=0;x<4;x++){
        alf[x] = *(const v8bf*)&Alo[(wm + x*16 + m16)*40 + q*8];
        blf[x] = *(const v8bf*)&Blo[(wn + x*16 + m16)*40 + q*8];
      }
      #pragma unroll
      for(int mi=0;mi<4;mi++)
        #pragma unroll
        for(int ni=0;ni<4;ni++){
          acc[mi][ni] = __builtin_amdgcn_mfma_f32_16x16x32_bf16(alf[mi], bhf[ni], acc[mi][ni], 0,0,0);
          acc[mi][ni] = __builtin_amdgcn_mfma_f32_16x16x32_bf16(ahf[mi], blf[ni], acc[mi][ni], 0,0,0);
        }
    }
    #pragma unroll
    for(int mi=0;mi<4;mi++)
      #pragma unroll
      for(int ni=0;ni<4;ni++)
        acc[mi][ni] = __builtin_amdgcn_mfma_f32_16x16x32_bf16(ahf[mi], bhf[ni], acc[mi][ni], 0,0,0);
    __syncthreads();
  }
  const int col16 = lane&15, rowq = lane>>4;
  #pragma unroll
  for(int mi=0;mi<4;mi++){
    #pragma unroll
    for(int ni=0;ni<4;ni++){
      int cj = bn + wn + ni*16 + col16;
      float sqj = sq[cj];
      #pragma unroll
      for(int r=0;r<4;r++){
        int ri = bm + wm + mi*16 + rowq*4 + r;
        float d2 = (sq[ri] + sqj) - 2.0f*acc[mi][ni][r];
        distH[(size_t)ri*NPTS + cj] = f2h(fmaxf(d2, 0.f));
      }
    }
  }
}

// ---------- fused: hidden GEMM (blocks 0..511) || knn half (blocks 512..1023) ----------
__global__ __launch_bounds__(256,2) void gemm_knn_k(const u16* __restrict__ A,
    const u16* __restrict__ Bt, const float* __restrict__ bias, u16* __restrict__ C,
    const u16* __restrict__ distH, const float* __restrict__ condF,
    int* __restrict__ nidx, int rowoff){
  __shared__ __align__(16) u16 gsm[12288];
  __shared__ float af[4][DF];
  __shared__ int   scnt[4];
  __shared__ int   cand[4][64];
  __shared__ u64   keys[4][64];
  const int bid = blockIdx.x;
  if(bid < 512){
    gemm_bt_body(A, Bt, bias, C, HID, HID, bid, gsm, gsm+8192);
  } else {
    const int wv = threadIdx.x>>6;
    const int row = rowoff + (bid-512)*4 + wv;
    knn_body(distH, condF, nidx, row, af[wv], &scnt[wv], cand[wv], keys[wv]);
  }
}

// ---------- standalone hidden GEMM (layer 4) ----------
__global__ __launch_bounds__(256,2) void gemm_bt_k(const u16* __restrict__ A,
    const u16* __restrict__ Bt, const float* __restrict__ bias, u16* __restrict__ C){
  __shared__ __align__(16) u16 As[8192];
  __shared__ __align__(16) u16 Bs[4096];
  gemm_bt_body(A, Bt, bias, C, HID, HID, blockIdx.x, As, Bs);
}

// ---------- final layer, split-K=4: Pp[s][r][c] = partial A@Wout^T ----------
__global__ __launch_bounds__(256,2) void gemm_out_k(const u16* __restrict__ A,
    const u16* __restrict__ Bt, float* __restrict__ Pp){
  __shared__ __align__(16) u16 As[128*32];
  __shared__ __align__(16) u16 Bs[64*32];
  const int bm = (blockIdx.x>>2)*128;
  const int k0 = (blockIdx.x&3)*256;
  float* P = Pp + (size_t)(blockIdx.x&3)*262144;
  const int tid = threadIdx.x, lane = tid&63, wave = tid>>6;
  const int wm = wave*32;
  int c0 = wave*128 + lane, c1 = c0 + 64;
  int ra0 = c0>>2, qa0 = c0&3, ra1 = c1>>2, qa1 = c1&3;
  int cb = wave*64 + lane;
  int rb = cb>>2, qb = cb&3;
  const u16* pA0 = A  + (size_t)(bm+ra0)*HID + qa0*8;
  const u16* pA1 = A  + (size_t)(bm+ra1)*HID + qa1*8;
  const u16* pB  = Bt + (size_t)rb*HID + qb*8;
  u16* lA0 = &As[(wave*128     )*8];
  u16* lA1 = &As[(wave*128 + 64)*8];
  u16* lB  = &Bs[(wave*64      )*8];
  const int m16 = lane&15, q = lane>>4;
  v4f acc[2][4] = {};
  for(int kb=k0; kb<k0+256; kb+=32){
    gl2lds16(pA0 + kb, lA0);
    gl2lds16(pA1 + kb, lA1);
    gl2lds16(pB  + kb, lB);
    __syncthreads();
    v8bf a[2], b[4];
    a[0] = *(const v8bf*)&As[(wm + m16)*32 + q*8];
    a[1] = *(const v8bf*)&As[(wm + 16 + m16)*32 + q*8];
    #pragma unroll
    for(int x=0;x<4;x++) b[x] = *(const v8bf*)&Bs[(x*16 + m16)*32 + q*8];
    #pragma unroll
    for(int mi=0;mi<2;mi++)
      #pragma unroll
      for(int ni=0;ni<4;ni++)
        acc[mi][ni] = __builtin_amdgcn_mfma_f32_16x16x32_bf16(a[mi], b[ni], acc[mi][ni], 0,0,0);
    __syncthreads();
  }
  const int col16 = lane&15, rowq = lane>>4;
  #pragma unroll
  for(int mi=0;mi<2;mi++){
    #pragma unroll
    for(int ni=0;ni<4;ni++){
      int cn = ni*16 + col16;
      #pragma unroll
      for(int r=0;r<4;r++){
        int rw = bm + wm + mi*16 + rowq*4 + r;
        P[(size_t)rw*DR + cn] = acc[mi][ni][r];
      }
    }
  }
}

// ---------- gather: out[i,k,:] = tens[j] - (bias + sum_s Pp[s][j]), j=nidx ----------
__global__ void gather_k(const float* __restrict__ Pp, const float* __restrict__ tensF,
                         const float* __restrict__ biasF, const int* __restrict__ nidx,
                         void* __restrict__ outv, const int* __restrict__ flag){
  const int fl = *flag;
  int e = blockIdx.x*256 + threadIdx.x;
  int m = e>>4;
  int c = (e&15)*4;
  int j = nidx[m] & (NPTS-1);
  size_t rc = (size_t)j*DR + c;
  float4 t  = *(const float4*)&tensF[rc];
  float4 b  = *(const float4*)&biasF[4096 + c];
  float4 p0 = *(const float4*)&Pp[rc];
  float4 p1 = *(const float4*)&Pp[262144 + rc];
  float4 p2 = *(const float4*)&Pp[524288 + rc];
  float4 p3 = *(const float4*)&Pp[786432 + rc];
  float4 v;
  v.x = t.x - (b.x + ((p0.x+p1.x)+(p2.x+p3.x)));
  v.y = t.y - (b.y + ((p0.y+p1.y)+(p2.y+p3.y)));
  v.z = t.z - (b.z + ((p0.z+p1.z)+(p2.z+p3.z)));
  v.w = t.w - (b.w + ((p0.w+p1.w)+(p2.w+p3.w)));
  if(fl){
    ushort4 o; o.x=f2bf(v.x); o.y=f2bf(v.y); o.z=f2bf(v.z); o.w=f2bf(v.w);
    *(ushort4*)&((u16*)outv)[(size_t)m*DR + c] = o;
  }else{
    *(float4*)&((float*)outv)[(size_t)m*DR + c] = v;
  }
}

// ---------- workspace layout (~68 MB of 256 MiB; no aliasing) ----------
constexpr size_t OFF_FLAG  = 0;
constexpr size_t OFF_SQ    = 256;
constexpr size_t OFF_NIDX  = OFF_SQ    + 16384;
constexpr size_t OFF_BIAS  = OFF_NIDX  + 163840;
constexpr size_t OFF_CONDF = OFF_BIAS  + 16640;
constexpr size_t OFF_TENSF = OFF_CONDF + 2097152;
constexpr size_t OFF_WTIN  = OFF_TENSF + 1048576;
constexpr size_t OFF_WT1   = OFF_WTIN  + 393216;
constexpr size_t OFF_WT2   = OFF_WT1   + 2097152;
constexpr size_t OFF_WT3   = OFF_WT2   + 2097152;
constexpr size_t OFF_WTO   = OFF_WT3   + 2097152;
constexpr size_t OFF_DIST  = OFF_WTO   + 131072;
constexpr size_t OFF_X     = OFF_DIST  + 33554432;   // fp16 dist
constexpr size_t OFF_A0    = OFF_X     + 1572864;
constexpr size_t OFF_A1    = OFF_A0    + 8388608;
constexpr size_t OFF_P     = OFF_A1    + 8388608;    // 4 x 1MB partials

extern "C" void kernel_launch(void* const* d_in, const int* in_sizes, int n_in,
                              void* d_out, int out_size, void* d_ws, size_t ws_size,
                              hipStream_t stream){
  char* ws = (char*)d_ws;
  int*   flag  = (int*)  (ws + OFF_FLAG);
  float* sqv   = (float*)(ws + OFF_SQ);
  int*   nidx  = (int*)  (ws + OFF_NIDX);
  float* biasF = (float*)(ws + OFF_BIAS);
  float* condF = (float*)(ws + OFF_CONDF);
  float* tensF = (float*)(ws + OFF_TENSF);
  u16*   Wt_in = (u16*)  (ws + OFF_WTIN);
  u16*   Wt1   = (u16*)  (ws + OFF_WT1);
  u16*   Wt2   = (u16*)  (ws + OFF_WT2);
  u16*   Wt3   = (u16*)  (ws + OFF_WT3);
  u16*   Wt_o  = (u16*)  (ws + OFF_WTO);
  u16*   distH = (u16*)  (ws + OFF_DIST);
  u16*   X     = (u16*)  (ws + OFF_X);
  u16*   A0    = (u16*)  (ws + OFF_A0);
  u16*   A1    = (u16*)  (ws + OFF_A1);
  float* Pp    = (float*)(ws + OFF_P);

  detect_k <<<1, 256, 0, stream>>>((const u16*)d_in[0], flag);
  prep_k   <<<8209, 256, 0, stream>>>(d_in[0], d_in[1],
                d_in[2], d_in[4], d_in[6], d_in[8], d_in[10],
                d_in[3], d_in[5], d_in[7], d_in[9], d_in[11],
                condF, tensF, biasF, Wt_in, Wt1, Wt2, Wt3, Wt_o, sqv, X, flag);
  // gemm1 || gram  (both depend only on prep)
  gram_g1_k<<<1536, 256, 0, stream>>>((const u16*)d_in[0], condF, sqv, distH, flag,
                                      X, Wt_in, biasF, A0);
  // gemm2 || knn rows 0..2047
  gemm_knn_k<<<1024, 256, 0, stream>>>(A0, Wt1, biasF+1024, A1, distH, condF, nidx, 0);
  // gemm3 || knn rows 2048..4095
  gemm_knn_k<<<1024, 256, 0, stream>>>(A1, Wt2, biasF+2048, A0, distH, condF, nidx, 2048);
  gemm_bt_k  <<<512, 256, 0, stream>>>(A0, Wt3, biasF+3072, A1);
  gemm_out_k <<<128, 256, 0, stream>>>(A1, Wt_o, Pp);
  gather_k   <<<2560, 256, 0, stream>>>(Pp, tensF, biasF, nidx, d_out, flag);
}